// Round 1
// baseline (521.823 us; speedup 1.0000x reference)
//
#include <hip/hip_runtime.h>

#define N_NODES 50000
#define N_EDGES 800000
#define D 64          // D_IN == D_OUT
#define ED 32         // EDGE_DIM
#define BN_EPS 1e-5f

// Workspace layout (floats):
// [0,64)    sums      (zeroed)
// [64,128)  sumsq     (zeroed)
// [128,192) scale
// [192,256) shift
// [256, 256+N*D)          agg  (zeroed)
// [256+N*D, 256+2*N*D)    h
// Total: 256 + 2*3,200,000 floats = ~25.6 MB

// ---------------------------------------------------------------------------
// Stage 1: per-edge  msg = x[src] + (ea @ We + be), atomic scatter into agg[dst]
// 256 threads = 4 edges x 64 features per pass. We in LDS (8KB).
__global__ __launch_bounds__(256) void edge_kernel(
    const float* __restrict__ x, const int* __restrict__ ei,
    const float* __restrict__ ea, const float* __restrict__ We,
    const float* __restrict__ be, float* __restrict__ agg)
{
    __shared__ float sWe[ED][D];    // 8 KB; read sWe[k][f]: f stride-1 -> 2-way (free)
    __shared__ float sAttr[4][ED];  // wave-broadcast reads

    const int tid = threadIdx.x;
    for (int i = tid; i < ED * D; i += 256) sWe[i >> 6][i & 63] = We[i];
    const int f = tid & 63;
    const int r = tid >> 6;
    const float bias = be[f];
    __syncthreads();

    const int stride = gridDim.x * 4;
    for (int e0 = blockIdx.x * 4; e0 < N_EDGES; e0 += stride) {
        __syncthreads();  // previous pass done reading sAttr
        if (tid < 128) {
            const int e = e0 + (tid >> 5);
            const int k = tid & 31;
            sAttr[tid >> 5][k] = (e < N_EDGES) ? ea[e * ED + k] : 0.f;
        }
        __syncthreads();
        const int e = e0 + r;
        if (e < N_EDGES) {
            const int src = ei[e];             // edge_index[0][e]
            const int dst = ei[N_EDGES + e];   // edge_index[1][e]
            float acc = bias + x[src * D + f];
            #pragma unroll
            for (int k = 0; k < ED; ++k)
                acc += sAttr[r][k] * sWe[k][f];
            unsafeAtomicAdd(&agg[dst * D + f], acc);  // HW global_atomic_add_f32
        }
    }
}

// ---------------------------------------------------------------------------
// Stage 2: h = (agg + x) @ W1 + b1; accumulate per-feature sum & sumsq.
__global__ __launch_bounds__(256) void mlp1_kernel(
    const float* __restrict__ x, const float* __restrict__ agg,
    const float* __restrict__ W1, const float* __restrict__ b1,
    float* __restrict__ h, float* __restrict__ sums, float* __restrict__ sumsq)
{
    __shared__ float sW[D][D];        // 16 KB
    __shared__ float sRow[4][D];
    __shared__ float sRed[2][4][D];   // 2 KB block reduction

    const int tid = threadIdx.x;
    for (int i = tid; i < D * D; i += 256) sW[i >> 6][i & 63] = W1[i];
    const int f = tid & 63;
    const int r = tid >> 6;
    const float bias = b1[f];
    float psum = 0.f, psq = 0.f;
    __syncthreads();

    const int stride = gridDim.x * 4;
    for (int n0 = blockIdx.x * 4; n0 < N_NODES; n0 += stride) {
        const int node = n0 + r;
        __syncthreads();
        if (node < N_NODES) sRow[r][f] = agg[node * D + f] + x[node * D + f];
        __syncthreads();
        if (node < N_NODES) {
            float acc = bias;
            #pragma unroll
            for (int k = 0; k < D; ++k)
                acc += sRow[r][k] * sW[k][f];
            h[node * D + f] = acc;
            psum += acc;
            psq  += acc * acc;
        }
    }
    sRed[0][r][f] = psum;
    sRed[1][r][f] = psq;
    __syncthreads();
    if (r == 0) {
        const float s = sRed[0][0][f] + sRed[0][1][f] + sRed[0][2][f] + sRed[0][3][f];
        const float q = sRed[1][0][f] + sRed[1][1][f] + sRed[1][2][f] + sRed[1][3][f];
        atomicAdd(&sums[f], s);
        atomicAdd(&sumsq[f], q);
    }
}

// ---------------------------------------------------------------------------
// Stage 3: finalize BN stats into per-feature scale/shift.
__global__ void stats_kernel(
    const float* __restrict__ sums, const float* __restrict__ sumsq,
    const float* __restrict__ gamma, const float* __restrict__ beta,
    float* __restrict__ scale, float* __restrict__ shift)
{
    const int f = threadIdx.x;  // 64 threads
    const float inv_n = 1.0f / (float)N_NODES;
    const float mean = sums[f] * inv_n;
    const float var  = sumsq[f] * inv_n - mean * mean;  // biased, like jnp.var
    const float sc   = gamma[f] * rsqrtf(var + BN_EPS);
    scale[f] = sc;
    shift[f] = beta[f] - mean * sc;
}

// ---------------------------------------------------------------------------
// Stage 4: out = relu(h*scale + shift) @ W2 + b2
__global__ __launch_bounds__(256) void mlp2_kernel(
    const float* __restrict__ h, const float* __restrict__ W2,
    const float* __restrict__ b2, const float* __restrict__ scale,
    const float* __restrict__ shift, float* __restrict__ out)
{
    __shared__ float sW[D][D];     // 16 KB
    __shared__ float sRow[4][D];
    __shared__ float sScale[D], sShift[D];

    const int tid = threadIdx.x;
    for (int i = tid; i < D * D; i += 256) sW[i >> 6][i & 63] = W2[i];
    if (tid < D) { sScale[tid] = scale[tid]; sShift[tid] = shift[tid]; }
    const int f = tid & 63;
    const int r = tid >> 6;
    const float bias = b2[f];
    __syncthreads();

    const int stride = gridDim.x * 4;
    for (int n0 = blockIdx.x * 4; n0 < N_NODES; n0 += stride) {
        const int node = n0 + r;
        __syncthreads();
        if (node < N_NODES) {
            const float v = h[node * D + f] * sScale[f] + sShift[f];
            sRow[r][f] = v > 0.f ? v : 0.f;
        }
        __syncthreads();
        if (node < N_NODES) {
            float acc = bias;
            #pragma unroll
            for (int k = 0; k < D; ++k)
                acc += sRow[r][k] * sW[k][f];
            out[node * D + f] = acc;
        }
    }
}

// ---------------------------------------------------------------------------
extern "C" void kernel_launch(void* const* d_in, const int* in_sizes, int n_in,
                              void* d_out, int out_size, void* d_ws, size_t ws_size,
                              hipStream_t stream) {
    const float* x     = (const float*)d_in[0];
    const int*   ei    = (const int*)  d_in[1];   // [2, E] int32
    const float* ea    = (const float*)d_in[2];
    const float* We    = (const float*)d_in[3];
    const float* be    = (const float*)d_in[4];
    const float* W1    = (const float*)d_in[5];
    const float* b1    = (const float*)d_in[6];
    const float* gamma = (const float*)d_in[7];
    const float* beta  = (const float*)d_in[8];
    const float* W2    = (const float*)d_in[9];
    const float* b2    = (const float*)d_in[10];

    float* ws    = (float*)d_ws;
    float* sums  = ws;
    float* sumsq = ws + 64;
    float* scale = ws + 128;
    float* shift = ws + 192;
    float* agg   = ws + 256;
    float* h     = agg + (size_t)N_NODES * D;

    // zero stats + agg (ws is poisoned 0xAA before every launch)
    hipMemsetAsync(ws, 0, (256 + (size_t)N_NODES * D) * sizeof(float), stream);

    edge_kernel <<<2048, 256, 0, stream>>>(x, ei, ea, We, be, agg);
    mlp1_kernel <<<512, 256, 0, stream>>>(x, agg, W1, b1, h, sums, sumsq);
    stats_kernel<<<1, 64, 0, stream>>>(sums, sumsq, gamma, beta, scale, shift);
    mlp2_kernel <<<512, 256, 0, stream>>>(h, W2, b2, scale, shift, (float*)d_out);
}